// Round 2
// baseline (2585.995 us; speedup 1.0000x reference)
//
#include <hip/hip_runtime.h>
#include <hip/hip_bf16.h>

#define NN 10000
#define NE 160000
#define INV_SQRT3 0.57735026918962576f
#define INV_SQRT2 0.70710678118654752f

__device__ __forceinline__ float silu_f(float x) { return x / (1.0f + __expf(-x)); }

// ---------------------------------------------------------------------------
// Kernel 1: node-wise pre-projection + gate.
//   s_p[n][v] = silu(xs[n] @ W_pre_s + b_pre_s)
//   v_p[n][v][c] = (sum_u xv[n][u][c] * W_pre_v[u][v]) * silu(norm*gw+gb)
// One block (1 wave, 64 threads) per node; thread t owns output channel t.
// ---------------------------------------------------------------------------
__global__ __launch_bounds__(64) void node_pre_kernel(
    const float* __restrict__ x,
    const float* __restrict__ W_pre_s, const float* __restrict__ b_pre_s,
    const float* __restrict__ W_pre_v,
    const float* __restrict__ gw_pre, const float* __restrict__ gb_pre,
    float* __restrict__ s_p, float* __restrict__ v_p)
{
    int n = blockIdx.x;
    int t = threadIdx.x;  // 0..63
    __shared__ float xs[64];
    __shared__ float xv[192];  // xv[u*3+c]
    const float4* row = (const float4*)(x + n * 256);
    {
        float4 v = row[t];  // elements t*4 .. t*4+3
        int idx = t * 4;
        float tmp[4] = {v.x, v.y, v.z, v.w};
#pragma unroll
        for (int i = 0; i < 4; i++) {
            int id = idx + i;
            if (id < 64) xs[id] = tmp[i];
            else         xv[id - 64] = tmp[i];
        }
    }
    __syncthreads();

    float acc_s = b_pre_s[t];
    float a0 = 0.f, a1 = 0.f, a2 = 0.f;
    for (int u = 0; u < 64; u++) {
        float xsu = xs[u];
        acc_s += xsu * W_pre_s[u * 64 + t];
        float wv = W_pre_v[u * 64 + t];
        a0 += xv[u * 3 + 0] * wv;
        a1 += xv[u * 3 + 1] * wv;
        a2 += xv[u * 3 + 2] * wv;
    }
    float nrm = sqrtf(a0 * a0 + a1 * a1 + a2 * a2 + 1e-12f);
    float g = silu_f(nrm * gw_pre[t] + gb_pre[t]);
    s_p[n * 64 + t] = silu_f(acc_s);
    float* vp = v_p + (n * 64 + t) * 3;
    vp[0] = a0 * g;
    vp[1] = a1 * g;
    vp[2] = a2 * g;
}

// ---------------------------------------------------------------------------
// Kernel 2: fully-fused edge pipeline. One wave (64 lanes) per edge;
// 4 waves per 256-thread block. Lane u owns channel u throughout.
// All barriers are block-uniform (identical control flow on all waves).
// ---------------------------------------------------------------------------
__global__ __launch_bounds__(256) void edge_kernel(
    const float* __restrict__ x,
    const float* __restrict__ edge_attr,
    const float* __restrict__ fij_in,
    const float* __restrict__ Ws1, const float* __restrict__ bs1,
    const float* __restrict__ Ws2, const float* __restrict__ bs2,
    const float* __restrict__ Wr1, const float* __restrict__ br1,
    const float* __restrict__ Wr2, const float* __restrict__ br2,
    const float* __restrict__ gw_post, const float* __restrict__ gb_post,
    const float* __restrict__ W_post_s, const float* __restrict__ W_post_v,
    const int* __restrict__ ei,
    const float* __restrict__ s_p, const float* __restrict__ v_p,
    float* __restrict__ out)
{
    __shared__ float s0[4][192];
    __shared__ float hb[4][128];
    __shared__ float osb[4][128];
    __shared__ __align__(16) float ovb[4][192][4];  // [row][c], padded to float4
    __shared__ float ob[4][256];

    int tid = threadIdx.x;
    int w = tid >> 6;   // wave within block
    int u = tid & 63;   // lane = channel
    int e = blockIdx.x * 4 + w;
    int src = ei[e];
    int dst = ei[NE + e];

    // ---- gather raw node features; build s0 = [xs_i | xs_j | dot_v] ----
    float xsi = x[src * 256 + u];
    float xsj = x[dst * 256 + u];
    float rvi0 = x[src * 256 + 64 + u * 3 + 0];
    float rvi1 = x[src * 256 + 64 + u * 3 + 1];
    float rvi2 = x[src * 256 + 64 + u * 3 + 2];
    float rvj0 = x[dst * 256 + 64 + u * 3 + 0];
    float rvj1 = x[dst * 256 + 64 + u * 3 + 1];
    float rvj2 = x[dst * 256 + 64 + u * 3 + 2];
    s0[w][u] = xsi;
    s0[w][64 + u] = xsj;
    s0[w][128 + u] = rvi0 * rvj0 + rvi1 * rvj1 + rvi2 * rvj2;
    __syncthreads();

    // ---- h1 = silu(s0 @ Ws1 + bs1); lane u -> outputs u, 64+u ----
    float acc1 = bs1[u];
    float acc2 = bs1[64 + u];
    for (int k = 0; k < 192; k++) {
        float s = s0[w][k];
        acc1 += s * Ws1[k * 128 + u];
        acc2 += s * Ws1[k * 128 + 64 + u];
    }
    hb[w][u] = silu_f(acc1);
    hb[w][64 + u] = silu_f(acc2);
    __syncthreads();

    // ---- tp_a[m*64+u] = h1 @ Ws2 + bs2 ----
    float tpa[5];
#pragma unroll
    for (int m = 0; m < 5; m++) tpa[m] = bs2[m * 64 + u];
    for (int k = 0; k < 128; k++) {
        float h = hb[w][k];
#pragma unroll
        for (int m = 0; m < 5; m++) tpa[m] += h * Ws2[k * 320 + m * 64 + u];
    }
    __syncthreads();  // before hb is overwritten with hr

    // ---- hr = silu(edge_attr @ Wr1 + br1) ----
    float accr1 = br1[u];
    float accr2 = br1[64 + u];
    for (int k = 0; k < 20; k++) {
        float a = edge_attr[e * 20 + k];  // wave-uniform broadcast load
        accr1 += a * Wr1[k * 128 + u];
        accr2 += a * Wr1[k * 128 + 64 + u];
    }
    hb[w][u] = silu_f(accr1);
    hb[w][64 + u] = silu_f(accr2);
    __syncthreads();

    // ---- tp_w = tp_a * (hr @ Wr2 + br2); lane u holds w1..w5[u] ----
    float wgt[5];
#pragma unroll
    for (int m = 0; m < 5; m++) wgt[m] = br2[m * 64 + u];
    for (int k = 0; k < 128; k++) {
        float h = hb[w][k];
#pragma unroll
        for (int m = 0; m < 5; m++) wgt[m] += h * Wr2[k * 320 + m * 64 + u];
    }
#pragma unroll
    for (int m = 0; m < 5; m++) wgt[m] *= tpa[m];

    // ---- gather gated node features ----
    float si = s_p[src * 64 + u];
    float sj = s_p[dst * 64 + u];
    const float* vip = v_p + (src * 64 + u) * 3;
    const float* vjp = v_p + (dst * 64 + u) * 3;
    float vi0 = vip[0], vi1 = vip[1], vi2 = vip[2];
    float vj0 = vjp[0], vj1 = vjp[1], vj2 = vjp[2];
    float dv = vi0 * vj0 + vi1 * vj1 + vi2 * vj2;

    // ---- tensor product + post gate ----
    float os1 = silu_f(wgt[0] * si * sj);
    float os2 = silu_f(wgt[3] * dv * INV_SQRT3);

    float r00 = wgt[1] * si * vj0, r01 = wgt[1] * si * vj1, r02 = wgt[1] * si * vj2;
    float r10 = wgt[2] * sj * vi0, r11 = wgt[2] * sj * vi1, r12 = wgt[2] * sj * vi2;
    float cx = vi1 * vj2 - vi2 * vj1;
    float cy = vi2 * vj0 - vi0 * vj2;
    float cz = vi0 * vj1 - vi1 * vj0;
    float r20 = wgt[4] * cx * INV_SQRT2;
    float r21 = wgt[4] * cy * INV_SQRT2;
    float r22 = wgt[4] * cz * INV_SQRT2;

    float n0 = sqrtf(r00 * r00 + r01 * r01 + r02 * r02 + 1e-12f);
    float g0 = silu_f(n0 * gw_post[u] + gb_post[u]);
    float n1 = sqrtf(r10 * r10 + r11 * r11 + r12 * r12 + 1e-12f);
    float g1 = silu_f(n1 * gw_post[64 + u] + gb_post[64 + u]);
    float n2 = sqrtf(r20 * r20 + r21 * r21 + r22 * r22 + 1e-12f);
    float g2 = silu_f(n2 * gw_post[128 + u] + gb_post[128 + u]);
    r00 *= g0; r01 *= g0; r02 *= g0;
    r10 *= g1; r11 *= g1; r12 *= g1;
    r20 *= g2; r21 *= g2; r22 *= g2;

    osb[w][u] = os1;
    osb[w][64 + u] = os2;
    ovb[w][u][0] = r00;       ovb[w][u][1] = r01;       ovb[w][u][2] = r02;
    ovb[w][64 + u][0] = r10;  ovb[w][64 + u][1] = r11;  ovb[w][64 + u][2] = r12;
    ovb[w][128 + u][0] = r20; ovb[w][128 + u][1] = r21; ovb[w][128 + u][2] = r22;
    __syncthreads();

    // ---- fij_s[u] = out_s @ W_post_s ----
    float fs = 0.f;
    for (int k = 0; k < 128; k++) fs += osb[w][k] * W_post_s[k * 64 + u];

    // ---- fij_v[u][c] = sum_k out_v[k][c] * W_post_v[k][u] ----
    float fv0 = 0.f, fv1 = 0.f, fv2 = 0.f;
    const float4* ovp = (const float4*)&ovb[w][0][0];
    for (int k = 0; k < 192; k++) {
        float wv = W_post_v[k * 64 + u];
        float4 vv = ovp[k];
        fv0 += vv.x * wv;
        fv1 += vv.y * wv;
        fv2 += vv.z * wv;
    }
    ob[w][u] = fs;
    ob[w][64 + u * 3 + 0] = fv0;
    ob[w][64 + u * 3 + 1] = fv1;
    ob[w][64 + u * 3 + 2] = fv2;
    __syncthreads();

    // ---- coalesced output: lane u writes 4 consecutive fp32 + residual ----
    float4 fin = ((const float4*)fij_in)[e * 64 + u];
    float4 o;
    o.x = ob[w][u * 4 + 0] + fin.x;
    o.y = ob[w][u * 4 + 1] + fin.y;
    o.z = ob[w][u * 4 + 2] + fin.z;
    o.w = ob[w][u * 4 + 3] + fin.w;
    ((float4*)out)[e * 64 + u] = o;
}

extern "C" void kernel_launch(void* const* d_in, const int* in_sizes, int n_in,
                              void* d_out, int out_size, void* d_ws, size_t ws_size,
                              hipStream_t stream)
{
    const float* x         = (const float*)d_in[0];
    const float* edge_attr = (const float*)d_in[1];
    const float* fij_in    = (const float*)d_in[2];
    const float* W_pre_s   = (const float*)d_in[3];
    const float* b_pre_s   = (const float*)d_in[4];
    const float* W_pre_v   = (const float*)d_in[5];
    const float* gw_pre    = (const float*)d_in[6];
    const float* gb_pre    = (const float*)d_in[7];
    const float* Ws1       = (const float*)d_in[8];
    const float* bs1       = (const float*)d_in[9];
    const float* Ws2       = (const float*)d_in[10];
    const float* bs2       = (const float*)d_in[11];
    const float* Wr1       = (const float*)d_in[12];
    const float* br1       = (const float*)d_in[13];
    const float* Wr2       = (const float*)d_in[14];
    const float* br2       = (const float*)d_in[15];
    const float* gw_post   = (const float*)d_in[16];
    const float* gb_post   = (const float*)d_in[17];
    const float* W_post_s  = (const float*)d_in[18];
    const float* W_post_v  = (const float*)d_in[19];
    const int*   ei        = (const int*)d_in[20];
    float* out = (float*)d_out;

    // workspace: s_p (N*64 fp32) + v_p (N*64*3 fp32) = 10.24 MB
    float* s_p = (float*)d_ws;
    float* v_p = s_p + NN * 64;

    node_pre_kernel<<<NN, 64, 0, stream>>>(x, W_pre_s, b_pre_s, W_pre_v,
                                           gw_pre, gb_pre, s_p, v_p);
    edge_kernel<<<NE / 4, 256, 0, stream>>>(x, edge_attr, fij_in,
                                            Ws1, bs1, Ws2, bs2,
                                            Wr1, br1, Wr2, br2,
                                            gw_post, gb_post, W_post_s, W_post_v,
                                            ei, s_p, v_p, out);
}